// Round 11
// baseline (118.477 us; speedup 1.0000x reference)
//
#include <hip/hip_runtime.h>
#include <hip/hip_bf16.h>

#define KS 5
#define NCH 32
#define IMH 256
#define IMW 256
#define TW 32
#define TH 8
#define HALO_W (TW + 4)
#define HALO_H (TH + 4)
#define HW (IMH * IMW)
#define OC_CHUNK 8

#define CHUNK 4
#define NCHUNK (NCH / CHUNK)
#define NPAIR (CHUNK / 2)                               // channel pairs per chunk
#define TILE_PAIRS (NPAIR * HALO_H * HALO_W)            // 864 float2
#define LOADS_P ((TILE_PAIRS + 255) / 256)              // 4

__device__ __forceinline__ float sigmoidf_(float x) {
    return 1.0f / (1.0f + __expf(-x));
}

// Packed fp32 FMA: d = a*b + c per 32-bit half. b is wave-uniform (weights)
// and rides in an SGPR pair (VOP3P allows 1 scalar source) -> 1 VALU instr
// replaces 2 scalar v_fma.
__device__ __forceinline__ float2 pk_fma(float2 a, float2 b, float2 c) {
    float2 d;
    asm("v_pk_fma_f32 %0, %1, %2, %3" : "=v"(d) : "v"(a), "s"(b), "v"(c));
    return d;
}

// ---------------------------------------------------------------------------
// Fully fused CIKA forward (R10 structure) + channel-pair packed stencils:
// tile staged as float2 of channels (c, c+1) -> one ds_read_b64 per tap
// feeds 2 channels; ak/au/ad accumulate via v_pk_fma_f32 (uniform weights in
// SGPRs). td stays scalar (divergent ksa operand). All per-channel results
// retire to per-thread LDS columns inside ROLLED chunk loops (R3-R10
// discipline: no register array incrementally written across an unrolled
// staging loop). LDS = 6.75K tile + 16K + 16K = 38.8 KB -> 4 blocks/CU.
// ---------------------------------------------------------------------------
__global__ __launch_bounds__(256) void cika_fused(
    const float* __restrict__ lower, const float* __restrict__ upper,
    const float* __restrict__ kca_dw_w, const float* __restrict__ kca_dw_b,
    const float* __restrict__ kca_m1_w, const float* __restrict__ kca_m1_b,
    const float* __restrict__ kca_m2_w, const float* __restrict__ kca_m2_b,
    const float* __restrict__ ksa_dw_w, const float* __restrict__ ksa_dw_b,
    const float* __restrict__ ksa_m1_w, const float* __restrict__ ksa_m1_b,
    const float* __restrict__ ksa_m2_w, const float* __restrict__ ksa_m2_b,
    const float* __restrict__ low_dyn_w, const float* __restrict__ low_dyn_b,
    const float* __restrict__ low_pw_w, const float* __restrict__ low_pw_b,
    const float* __restrict__ up_dw_w, const float* __restrict__ up_dw_b,
    const float* __restrict__ up_pw_w, const float* __restrict__ up_pw_b,
    float* __restrict__ out_low, float* __restrict__ out_up)
{
    __shared__ float2 tile2[TILE_PAIRS];               //  6912 B
    __shared__ __hip_bfloat16 dwk_td_lds[NCH][256];    // 16 KB: relu(ksa_dw), later td
    __shared__ __hip_bfloat16 dwu_lds[NCH][256];       // 16 KB: up_dw result

    const int tid = threadIdx.x;
    const int tx = tid & (TW - 1);
    const int ty = tid >> 5;
    const int tile_x = blockIdx.x * TW;
    const int tile_y = blockIdx.y * TH;
    const int n = blockIdx.z;
    const int x = tile_x + tx, y = tile_y + ty;
    const int pix = y * IMW + x;

    const float* lob = lower + (size_t)n * NCH * HW;
    const float* upb = upper + (size_t)n * NCH * HW;

    // hoisted staging geometry (shared by both passes).
    // goff = pair*2*HW + spatial offset; second channel of the pair is +HW.
    int goff[LOADS_P];
    bool gok[LOADS_P];
    #pragma unroll
    for (int l = 0; l < LOADS_P; ++l) {
        const int idx = tid + l * 256;
        int p = idx / (HALO_H * HALO_W);
        int r = idx - p * (HALO_H * HALO_W);
        int hy = r / HALO_W, hx = r - hy * HALO_W;
        int gy = tile_y + hy - 2, gx = tile_x + hx - 2;
        gok[l] = (idx < TILE_PAIRS) && (gy >= 0) && (gy < IMH) && (gx >= 0) && (gx < IMW);
        goff[l] = p * 2 * HW + gy * IMW + gx;
    }

    // ================= Phase 1: upper pass (rolled, packed) =================
    {
        float2 pre[LOADS_P];
        #pragma unroll
        for (int l = 0; l < LOADS_P; ++l) {
            pre[l].x = gok[l] ? upb[(size_t)0 + goff[l]] : 0.0f;
            pre[l].y = gok[l] ? upb[(size_t)HW + goff[l]] : 0.0f;
        }

        #pragma unroll 1
        for (int ck = 0; ck < NCHUNK; ++ck) {
            __syncthreads();
            #pragma unroll
            for (int l = 0; l < LOADS_P; ++l) {
                const int idx = tid + l * 256;
                if (idx < TILE_PAIRS) tile2[idx] = pre[l];
            }
            __syncthreads();
            if (ck + 1 < NCHUNK) {
                const size_t base = (size_t)(ck + 1) * CHUNK * HW;
                #pragma unroll
                for (int l = 0; l < LOADS_P; ++l) {
                    pre[l].x = gok[l] ? upb[base + goff[l]] : 0.0f;
                    pre[l].y = gok[l] ? upb[base + HW + goff[l]] : 0.0f;
                }
            }
            const int c0 = ck * CHUNK;
            #pragma unroll
            for (int p = 0; p < NPAIR; ++p) {
                const int c = c0 + p * 2;
                float2 ak2 = make_float2(ksa_dw_b[c], ksa_dw_b[c + 1]);
                float2 au2 = make_float2(up_dw_b[c], up_dw_b[c + 1]);
                const float2* tp2 = tile2 + p * (HALO_H * HALO_W) + ty * HALO_W + tx;
                #pragma unroll
                for (int t = 0; t < 25; ++t) {
                    const int i = t / 5, j = t % 5;
                    float2 wv = tp2[i * HALO_W + j];
                    float2 wk = make_float2(ksa_dw_w[c * 25 + t], ksa_dw_w[(c + 1) * 25 + t]);
                    float2 wu = make_float2(up_dw_w[c * 25 + t], up_dw_w[(c + 1) * 25 + t]);
                    ak2 = pk_fma(wv, wk, ak2);
                    au2 = pk_fma(wv, wu, au2);
                }
                dwk_td_lds[c][tid]     = __float2bfloat16(fmaxf(ak2.x, 0.0f));
                dwk_td_lds[c + 1][tid] = __float2bfloat16(fmaxf(ak2.y, 0.0f));
                dwu_lds[c][tid]        = __float2bfloat16(au2.x);
                dwu_lds[c + 1][tid]    = __float2bfloat16(au2.y);
            }
        }
    }

    // ================= Phase 2: KSA MLP 32->50(relu)->25(sigmoid) =================
    float ksa[25];
    {
        float dwk[NCH];
        #pragma unroll
        for (int c = 0; c < NCH; ++c)
            dwk[c] = __bfloat162float(dwk_td_lds[c][tid]);
        #pragma unroll
        for (int k = 0; k < 25; ++k) ksa[k] = ksa_m2_b[k];
        for (int h = 0; h < 50; ++h) {
            float hv = ksa_m1_b[h];
            #pragma unroll
            for (int c = 0; c < NCH; ++c)
                hv = fmaf(ksa_m1_w[h * NCH + c], dwk[c], hv);
            hv = fmaxf(hv, 0.0f);
            #pragma unroll
            for (int k = 0; k < 25; ++k)
                ksa[k] = fmaf(ksa_m2_w[k * 50 + h], hv, ksa[k]);
        }
        #pragma unroll
        for (int k = 0; k < 25; ++k) ksa[k] = sigmoidf_(ksa[k]);
    }
    // dwk_td_lds now dead as dwk -> reused for td (same-thread columns only).

    // ================= Phase 3: lower pass (rolled, packed ad; scalar td) =================
    float hv8[8];
    #pragma unroll
    for (int h = 0; h < 8; ++h) hv8[h] = kca_m1_b[h];
    {
        float2 pre[LOADS_P];
        #pragma unroll
        for (int l = 0; l < LOADS_P; ++l) {
            pre[l].x = gok[l] ? lob[(size_t)0 + goff[l]] : 0.0f;
            pre[l].y = gok[l] ? lob[(size_t)HW + goff[l]] : 0.0f;
        }

        #pragma unroll 1
        for (int ck = 0; ck < NCHUNK; ++ck) {
            __syncthreads();
            #pragma unroll
            for (int l = 0; l < LOADS_P; ++l) {
                const int idx = tid + l * 256;
                if (idx < TILE_PAIRS) tile2[idx] = pre[l];
            }
            __syncthreads();
            if (ck + 1 < NCHUNK) {
                const size_t base = (size_t)(ck + 1) * CHUNK * HW;
                #pragma unroll
                for (int l = 0; l < LOADS_P; ++l) {
                    pre[l].x = gok[l] ? lob[base + goff[l]] : 0.0f;
                    pre[l].y = gok[l] ? lob[base + HW + goff[l]] : 0.0f;
                }
            }
            const int c0 = ck * CHUNK;
            #pragma unroll
            for (int p = 0; p < NPAIR; ++p) {
                const int c = c0 + p * 2;
                float2 ad2 = make_float2(kca_dw_b[c], kca_dw_b[c + 1]);
                float tdx = low_dyn_b[c];
                float tdy = low_dyn_b[c + 1];
                const float2* tp2 = tile2 + p * (HALO_H * HALO_W) + ty * HALO_W + tx;
                #pragma unroll
                for (int t = 0; t < 25; ++t) {
                    const int i = t / 5, j = t % 5;
                    float2 wv = tp2[i * HALO_W + j];
                    float2 wd = make_float2(kca_dw_w[c * 25 + t], kca_dw_w[(c + 1) * 25 + t]);
                    ad2 = pk_fma(wv, wd, ad2);
                    tdx = fmaf(wv.x * low_dyn_w[c * 25 + t], ksa[t], tdx);
                    tdy = fmaf(wv.y * low_dyn_w[(c + 1) * 25 + t], ksa[t], tdy);
                }
                float adx = fmaxf(ad2.x, 0.0f);
                float ady = fmaxf(ad2.y, 0.0f);
                #pragma unroll
                for (int h = 0; h < 8; ++h) {
                    hv8[h] = fmaf(kca_m1_w[h * NCH + c], adx, hv8[h]);
                    hv8[h] = fmaf(kca_m1_w[h * NCH + c + 1], ady, hv8[h]);
                }
                dwk_td_lds[c][tid]     = __float2bfloat16(tdx);
                dwk_td_lds[c + 1][tid] = __float2bfloat16(tdy);
            }
        }
    }

    // ================= Phase 4: out_low = low_pw @ td + b =================
    {
        float tdv[NCH];
        #pragma unroll
        for (int c = 0; c < NCH; ++c)
            tdv[c] = __bfloat162float(dwk_td_lds[c][tid]);
        float* ol = out_low + (size_t)n * NCH * HW + pix;
        #pragma unroll
        for (int oc = 0; oc < NCH / OC_CHUNK; ++oc) {
            float acc[OC_CHUNK];
            #pragma unroll
            for (int oo = 0; oo < OC_CHUNK; ++oo)
                acc[oo] = low_pw_b[oc * OC_CHUNK + oo];
            #pragma unroll
            for (int c = 0; c < NCH; ++c)
                #pragma unroll
                for (int oo = 0; oo < OC_CHUNK; ++oo)
                    acc[oo] = fmaf(low_pw_w[(oc * OC_CHUNK + oo) * NCH + c], tdv[c], acc[oo]);
            #pragma unroll
            for (int oo = 0; oo < OC_CHUNK; ++oo)
                ol[(size_t)(oc * OC_CHUNK + oo) * HW] = acc[oo];
        }
    }

    // ================= Phase 5: KCA finish =================
    float kca[NCH];
    #pragma unroll
    for (int h = 0; h < 8; ++h) hv8[h] = fmaxf(hv8[h], 0.0f);
    #pragma unroll
    for (int k = 0; k < NCH; ++k) {
        float a = kca_m2_b[k];
        #pragma unroll
        for (int h = 0; h < 8; ++h)
            a = fmaf(kca_m2_w[k * 8 + h], hv8[h], a);
        kca[k] = sigmoidf_(a);
    }

    // ================= Phase 6: up path =================
    {
        float t2[NCH];
        #pragma unroll
        for (int c = 0; c < NCH; ++c)
            t2[c] = __bfloat162float(dwu_lds[c][tid]) * kca[c];
        float* ou = out_up + (size_t)n * NCH * HW + pix;
        #pragma unroll
        for (int oc = 0; oc < NCH / OC_CHUNK; ++oc) {
            float acc[OC_CHUNK];
            #pragma unroll
            for (int oo = 0; oo < OC_CHUNK; ++oo)
                acc[oo] = up_pw_b[oc * OC_CHUNK + oo];
            #pragma unroll
            for (int c = 0; c < NCH; ++c)
                #pragma unroll
                for (int oo = 0; oo < OC_CHUNK; ++oo)
                    acc[oo] = fmaf(up_pw_w[(oc * OC_CHUNK + oo) * NCH + c], t2[c], acc[oo]);
            #pragma unroll
            for (int oo = 0; oo < OC_CHUNK; ++oo)
                ou[(size_t)(oc * OC_CHUNK + oo) * HW] = acc[oo];
        }
    }
}

extern "C" void kernel_launch(void* const* d_in, const int* in_sizes, int n_in,
                              void* d_out, int out_size, void* d_ws, size_t ws_size,
                              hipStream_t stream) {
    const float* lower    = (const float*)d_in[0];
    const float* upper    = (const float*)d_in[1];
    const float* kca_dw_w = (const float*)d_in[2];
    const float* kca_dw_b = (const float*)d_in[3];
    const float* kca_m1_w = (const float*)d_in[4];
    const float* kca_m1_b = (const float*)d_in[5];
    const float* kca_m2_w = (const float*)d_in[6];
    const float* kca_m2_b = (const float*)d_in[7];
    const float* ksa_dw_w = (const float*)d_in[8];
    const float* ksa_dw_b = (const float*)d_in[9];
    const float* ksa_m1_w = (const float*)d_in[10];
    const float* ksa_m1_b = (const float*)d_in[11];
    const float* ksa_m2_w = (const float*)d_in[12];
    const float* ksa_m2_b = (const float*)d_in[13];
    const float* low_dyn_w = (const float*)d_in[14];
    const float* low_dyn_b = (const float*)d_in[15];
    const float* low_pw_w  = (const float*)d_in[16];
    const float* low_pw_b  = (const float*)d_in[17];
    const float* up_dw_w   = (const float*)d_in[18];
    const float* up_dw_b   = (const float*)d_in[19];
    const float* up_pw_w   = (const float*)d_in[20];
    const float* up_pw_b   = (const float*)d_in[21];

    const int N = in_sizes[0] / (NCH * HW);
    float* out_low = (float*)d_out;
    float* out_up  = (float*)d_out + (size_t)N * NCH * HW;

    dim3 grid(IMW / TW, IMH / TH, N);
    cika_fused<<<grid, dim3(256), 0, stream>>>(
        lower, upper,
        kca_dw_w, kca_dw_b, kca_m1_w, kca_m1_b, kca_m2_w, kca_m2_b,
        ksa_dw_w, ksa_dw_b, ksa_m1_w, ksa_m1_b, ksa_m2_w, ksa_m2_b,
        low_dyn_w, low_dyn_b, low_pw_w, low_pw_b,
        up_dw_w, up_dw_b, up_pw_w, up_pw_b,
        out_low, out_up);
}